// Round 14
// baseline (774.425 us; speedup 1.0000x reference)
//
#include <hip/hip_runtime.h>
#include <cstdint>
#include <cstddef>

#define B_   64
#define T_   256
#define DIN_ 128
#define H_   256
#define G3_  768   // 3*H

// ---------- helpers ----------
__device__ __forceinline__ unsigned short f2h(float f) {
  _Float16 h = (_Float16)f;              // v_cvt_f16_f32 (RNE)
  return __builtin_bit_cast(unsigned short, h);
}

// acc += dot(v2f16(a), v2f16(b)) in fp32
__device__ __forceinline__ void dot2f(float& acc, unsigned a, unsigned b) {
  asm("v_dot2_f32_f16 %0, %1, %2, %0" : "+v"(acc) : "v"(a), "v"(b));
}

__device__ __forceinline__ int load_acq(const int* p) {
  return __hip_atomic_load(p, __ATOMIC_ACQUIRE, __HIP_MEMORY_SCOPE_AGENT);
}

// ---------- prep ----------
// Wreg layout for 512-thread gru: thread t: ks = t>>7, og = t&127.
// w[j] (j = a*32+qp): Wreg[(j4*512+t)*4+(j&3)] = f16pair(W_hh[a*128+og][64ks+2qp],..+1)
// WheadT layout: [c][k]. Also zeroes the xproj->gru progress flags.
__global__ __launch_bounds__(256) void prep_kernel(
    const float* __restrict__ W_ih, const float* __restrict__ W_hh,
    const float* __restrict__ W_mz, const float* __restrict__ W_mx,
    const float* __restrict__ W_pz, const float* __restrict__ W_cx,
    float* __restrict__ WT_ih, float* __restrict__ WheadT,
    unsigned* __restrict__ Wreg, int* __restrict__ done) {
  int i = blockIdx.x * 256 + threadIdx.x;
  if (i < 512) done[i] = 0;              // flags (ws is re-poisoned every call)
  if (i < 98304) {                       // WT_ih[k*768+g] = W_ih[g*128+k]
    int k = i / 768, g = i % 768;
    WT_ih[i] = W_ih[g * 128 + k];
  } else if (i < 98304 + 24576) {        // WheadT[c*256+k]
    int j = i - 98304;
    int c = j >> 8, k = j & 255;
    float v;
    if (c < 8)       v = W_mz[c * 256 + k];
    else if (c < 16) v = W_mx[(c - 8) * 256 + k];
    else if (c < 32) v = W_pz[(c - 16) * 256 + k];
    else             v = W_cx[(c - 32) * 256 + k];
    WheadT[j] = v;
  } else {                               // W_hh fp16-pair repack
    int m = i - 122880;                  // 0..98303
    int c = m & 3, n = m >> 2;
    int t = n & 511, j4 = n >> 9;        // j4 in [0,48)
    int j = 4 * j4 + c;                  // [0,192)
    int a = j >> 5, qp = j & 31;
    int o = a * 128 + (t & 127);
    int k0 = ((t >> 7) << 6) + 2 * qp;
    unsigned short lo = f2h(W_hh[o * 256 + k0]);
    unsigned short hi = f2h(W_hh[o * 256 + k0 + 1]);
    Wreg[m] = ((unsigned)hi << 16) | (unsigned)lo;
  }
}

// ---------- fused: gru (blocks 0-63) + xproj (blocks 64-319) ----------
// xproj block j covers rows [64j, 64j+64); sets done[j] (device-release) when
// its xp rows are written. gru block b consumes xp rows b*256+t, waiting on
// done[4b + (t+2)>>6] at t in {pre-loop, 62, 126, 190}. xproj never waits ->
// no deadlock; waves_per_eu(2,2) = 1 block/CU -> no gru/xproj CU sharing.
__global__ __launch_bounds__(512) __attribute__((amdgpu_waves_per_eu(2, 2)))
void fused_kernel(
    const float* __restrict__ y, const float* __restrict__ WT_ih,
    const float* __restrict__ b_ih, float* xp,
    const unsigned* Wreg, const float* __restrict__ b_hh,
    float* enc, int* done) {
  __shared__ alignas(16) unsigned char smem[34816];
  int tid = threadIdx.x;

  if (blockIdx.x >= 64) {                // ================= xproj =================
    int j = blockIdx.x - 64;
    int row0 = j * 64;
    float* ylds = (float*)smem;          // [64][132]
    const float4* y4 = (const float4*)(y + (size_t)row0 * DIN_);
#pragma unroll
    for (int i = 0; i < 4; ++i) {
      int idx = i * 512 + tid;           // 2048 float4 = 64x128
      float4 v = y4[idx];
      int r = idx >> 5, c4 = (idx & 31) * 4;
      ylds[r * 132 + c4 + 0] = v.x; ylds[r * 132 + c4 + 1] = v.y;
      ylds[r * 132 + c4 + 2] = v.z; ylds[r * 132 + c4 + 3] = v.w;
    }
    __syncthreads();
    int tx = tid & 15, ty = tid >> 4;    // ty in [0,32): thread 2 rows x 8 cols
    for (int c = 0; c < 6; ++c) {
      int col0 = c * 128 + tx * 8;
      float acc[2][8];
#pragma unroll
      for (int a = 0; a < 2; ++a)
#pragma unroll
        for (int b2 = 0; b2 < 8; ++b2) acc[a][b2] = 0.f;
#pragma unroll 4
      for (int k = 0; k < 128; ++k) {
        float4 w0 = *(const float4*)&WT_ih[k * 768 + col0];
        float4 w1 = *(const float4*)&WT_ih[k * 768 + col0 + 4];
        float a0 = ylds[(ty * 2 + 0) * 132 + k];
        float a1 = ylds[(ty * 2 + 1) * 132 + k];
        acc[0][0] += a0 * w0.x; acc[0][1] += a0 * w0.y; acc[0][2] += a0 * w0.z; acc[0][3] += a0 * w0.w;
        acc[0][4] += a0 * w1.x; acc[0][5] += a0 * w1.y; acc[0][6] += a0 * w1.z; acc[0][7] += a0 * w1.w;
        acc[1][0] += a1 * w0.x; acc[1][1] += a1 * w0.y; acc[1][2] += a1 * w0.z; acc[1][3] += a1 * w0.w;
        acc[1][4] += a1 * w1.x; acc[1][5] += a1 * w1.y; acc[1][6] += a1 * w1.z; acc[1][7] += a1 * w1.w;
      }
      float4 b0 = *(const float4*)&b_ih[col0];
      float4 b1 = *(const float4*)&b_ih[col0 + 4];
#pragma unroll
      for (int a = 0; a < 2; ++a) {
        int row = row0 + ty * 2 + a;
        float4 o0, o1;
        o0.x = acc[a][0] + b0.x; o0.y = acc[a][1] + b0.y; o0.z = acc[a][2] + b0.z; o0.w = acc[a][3] + b0.w;
        o1.x = acc[a][4] + b1.x; o1.y = acc[a][5] + b1.y; o1.z = acc[a][6] + b1.z; o1.w = acc[a][7] + b1.w;
        *(float4*)&xp[(size_t)row * G3_ + col0] = o0;
        *(float4*)&xp[(size_t)row * G3_ + col0 + 4] = o1;
      }
    }
    __syncthreads();                     // all stores drained (vmcnt(0) at barrier)
    if (tid == 0) {
      __threadfence();                   // device-release for the block's writes
      __hip_atomic_store(&done[j], 1, __ATOMIC_RELEASE, __HIP_MEMORY_SCOPE_AGENT);
    }
    return;
  }

  // ================= gru (R11 structure, + flag waits) =================
  int ks = tid >> 7;                     // wave-uniform k-slice [64ks,64ks+64)
  int og = tid & 127;                    // outputs a*128+og
  int b = blockIdx.x;
  unsigned short* hsb = (unsigned short*)smem;      // [256] fp16 h
  float* part = (float*)(smem + 512);               // [3104]
  unsigned w[192];
  const uint4* W4 = (const uint4*)Wreg;
#pragma unroll
  for (int j4 = 0; j4 < 48; ++j4) {
    uint4 q = W4[j4 * 512 + tid];        // coalesced dwordx4, once
    w[4 * j4 + 0] = q.x; w[4 * j4 + 1] = q.y;
    w[4 * j4 + 2] = q.z; w[4 * j4 + 3] = q.w;
  }
  const float* xpb = xp + (size_t)b * (T_ * G3_);
  float* encb = enc + (size_t)b * (T_ * H_);
  if (tid == 0) { while (load_acq(&done[4 * b]) == 0) {} }   // rows [0,64)
  __syncthreads();
  float bhr = 0.f, bhz = 0.f, bhn = 0.f, hold = 0.f;
  float xr0 = 0.f, xz0 = 0.f, xn0 = 0.f, xr1 = 0.f, xz1 = 0.f, xn1 = 0.f;
  if (tid < 256) {
    bhr = b_hh[tid]; bhz = b_hh[256 + tid]; bhn = b_hh[512 + tid];
    xr0 = xpb[tid];        xz0 = xpb[256 + tid];        xn0 = xpb[512 + tid];
    xr1 = xpb[768 + tid];  xz1 = xpb[1024 + tid];       xn1 = xpb[1280 + tid];
    hsb[tid] = 0;                        // h0 = 0
  }
  __syncthreads();
  for (int t = 0; t < T_; ++t) {
    if (t == 62 || t == 126 || t == 190) {         // next 64-row xp chunk ready?
      if (tid == 0) {
        const int* f = &done[4 * b + ((t + 2) >> 6)];
        while (load_acq(f) == 0) {}
      }
      __syncthreads();
    }
    asm volatile("" ::: "memory");       // forbid w[] reload from Wreg
    float xr2 = 0.f, xz2 = 0.f, xn2 = 0.f;
    if (tid < 256 && t < 254) {          // prefetch t+2 (no cross-batch overrun)
      int base = (t + 2) * G3_ + tid;
      xr2 = xpb[base]; xz2 = xpb[base + 256]; xn2 = xpb[base + 512];
    }
    float p0 = 0.f, p1 = 0.f, p2 = 0.f, p3 = 0.f, p4 = 0.f, p5 = 0.f;
    const uint4* hs = ((const uint4*)hsb) + (ks << 3);   // 8 uint4 = 64 fp16
#pragma unroll
    for (int r = 0; r < 8; ++r) {
      uint4 hq = hs[r];                  // uniform addr -> LDS broadcast
      dot2f(p0, hq.x, w[(r << 2) + 0]);
      dot2f(p0, hq.y, w[(r << 2) + 1]);
      dot2f(p0, hq.z, w[(r << 2) + 2]);
      dot2f(p0, hq.w, w[(r << 2) + 3]);
      dot2f(p1, hq.x, w[32 + (r << 2) + 0]);
      dot2f(p1, hq.y, w[32 + (r << 2) + 1]);
      dot2f(p1, hq.z, w[32 + (r << 2) + 2]);
      dot2f(p1, hq.w, w[32 + (r << 2) + 3]);
      dot2f(p2, hq.x, w[64 + (r << 2) + 0]);
      dot2f(p2, hq.y, w[64 + (r << 2) + 1]);
      dot2f(p2, hq.z, w[64 + (r << 2) + 2]);
      dot2f(p2, hq.w, w[64 + (r << 2) + 3]);
      dot2f(p3, hq.x, w[96 + (r << 2) + 0]);
      dot2f(p3, hq.y, w[96 + (r << 2) + 1]);
      dot2f(p3, hq.z, w[96 + (r << 2) + 2]);
      dot2f(p3, hq.w, w[96 + (r << 2) + 3]);
      dot2f(p4, hq.x, w[128 + (r << 2) + 0]);
      dot2f(p4, hq.y, w[128 + (r << 2) + 1]);
      dot2f(p4, hq.z, w[128 + (r << 2) + 2]);
      dot2f(p4, hq.w, w[128 + (r << 2) + 3]);
      dot2f(p5, hq.x, w[160 + (r << 2) + 0]);
      dot2f(p5, hq.y, w[160 + (r << 2) + 1]);
      dot2f(p5, hq.z, w[160 + (r << 2) + 2]);
      dot2f(p5, hq.w, w[160 + (r << 2) + 3]);
    }
    int pb = ks * 776 + og;
    part[pb]       = p0;  part[pb + 128] = p1;
    part[pb + 256] = p2;  part[pb + 384] = p3;
    part[pb + 512] = p4;  part[pb + 640] = p5;
    __syncthreads();                     // partials visible; h reads done
    if (tid < 256) {
      int u = tid;
      float prer = bhr + ((part[u] + part[776 + u]) +
                          (part[1552 + u] + part[2328 + u]));
      float prez = bhz + ((part[256 + u] + part[1032 + u]) +
                          (part[1808 + u] + part[2584 + u]));
      float pren = bhn + ((part[512 + u] + part[1288 + u]) +
                          (part[2064 + u] + part[2840 + u]));
      float r_ = 1.f / (1.f + __expf(-(xr0 + prer)));
      float z_ = 1.f / (1.f + __expf(-(xz0 + prez)));
      float a = xn0 + r_ * pren;
      a = fminf(15.f, fmaxf(-15.f, a));
      float e = __expf(2.f * a);
      float n = (e - 1.f) / (e + 1.f);   // tanh
      float hnew = (1.f - z_) * n + z_ * hold;
      hold = hnew;                       // exact fp32 state in-register
      encb[t * H_ + u] = hnew;
      hsb[u] = f2h(hnew);
      xr0 = xr1; xz0 = xz1; xn0 = xn1;
      xr1 = xr2; xz1 = xz2; xn1 = xn2;
    }
    __syncthreads();                     // new h visible; part consumed
  }
}

// ---------- anchor[b][d] = enc[b,0,:] . W_mx[d] + b_mx[d],  d<2 ----------
__global__ __launch_bounds__(256) void anchor_kernel(
    const float* __restrict__ enc, const float* __restrict__ W_mx,
    const float* __restrict__ b_mx, float* __restrict__ anchor) {
  __shared__ float red[4];
  int bid = blockIdx.x, tid = threadIdx.x;
  int b = bid >> 1, d = bid & 1;
  float v = enc[(size_t)b * (T_ * H_) + tid] * W_mx[d * 256 + tid];
#pragma unroll
  for (int off = 32; off >= 1; off >>= 1) v += __shfl_down(v, off, 64);
  if ((tid & 63) == 0) red[tid >> 6] = v;
  __syncthreads();
  if (tid == 0)
    anchor[b * 2 + d] = b_mx[d] + ((red[0] + red[1]) + (red[2] + red[3]));
}

// ---------- heads (blocks 0-511) + upper-half chol zero (512-703) ----------
__global__ __launch_bounds__(384) void heads_kernel(
    const float* __restrict__ enc, const float* __restrict__ WheadT,
    const float* __restrict__ b_mz, const float* __restrict__ b_mx,
    const float* __restrict__ b_pz, const float* __restrict__ b_cx,
    const float* __restrict__ anchor,
    float* __restrict__ out_meanz, float* __restrict__ out_meanx,
    float* __restrict__ out_covx, float* __restrict__ stage,
    float4* __restrict__ chol4) {
  if (blockIdx.x >= 512) {               // zero chol floats [16777216, 33554432)
    float4* cz = chol4 + 4194304;
    int idx = (blockIdx.x - 512) * 384 + threadIdx.x;
    float4 z = {0.f, 0.f, 0.f, 0.f};
    for (; idx < 4194304; idx += 192 * 384) cz[idx] = z;
    return;
  }
  __shared__ float el[32 * 256];         // 32 KB
  int tid = threadIdx.x;
  int row0 = blockIdx.x * 32;
  const float4* e4 = (const float4*)(enc + (size_t)row0 * 256);
  float4* el4 = (float4*)el;
#pragma unroll
  for (int i = 0; i < 6; ++i) {
    int idx = i * 384 + tid;             // 2048 float4 = 32x64
    if (idx < 2048) el4[idx] = e4[idx];
  }
  __syncthreads();
  int rg = tid / 96, c = tid - rg * 96;  // rg in [0,4), c in [0,96)
  const float4* Wc = (const float4*)(WheadT + c * 256);
  float acc[8];
#pragma unroll
  for (int r = 0; r < 8; ++r) acc[r] = 0.f;
  for (int k4 = 0; k4 < 64; ++k4) {
    float4 w4 = Wc[k4];
#pragma unroll
    for (int r = 0; r < 8; ++r) {
      float4 ev = el4[(rg * 8 + r) * 64 + k4];
      acc[r] += w4.x * ev.x; acc[r] += w4.y * ev.y;
      acc[r] += w4.z * ev.z; acc[r] += w4.w * ev.w;
    }
  }
#pragma unroll
  for (int r = 0; r < 8; ++r) {
    int row = row0 + rg * 8 + r;
    int bb = row >> 8;
    float a_ = acc[r];
    if (c < 8) {
      out_meanz[(size_t)row * 8 + c] = a_ + b_mz[c];
    } else if (c < 16) {
      int d = c - 8;
      float v = a_ + b_mx[d];
      if (d < 2) v -= anchor[bb * 2 + d];
      out_meanx[(size_t)row * 8 + d] = v;
    } else if (c < 32) {
      int d = c - 16;
      float v = a_ + b_pz[d];
      if (d < 8)                          // diag: softplus (stable)
        v = (v > 0.f) ? (v + log1pf(__expf(-v))) : log1pf(__expf(v));
      stage[(size_t)row * 16 + d] = v;
    } else {
      int d = c - 32;
      out_covx[(size_t)row * 64 + d] = a_ + b_cx[d];
    }
  }
}

// ---------- final chol: fused zero+scatter lower half, scatter upper half ----
__global__ __launch_bounds__(256) void chol_fin(
    const float* __restrict__ stage, float4* __restrict__ chol) {
  int i = blockIdx.x * 256 + threadIdx.x;
  int stride = gridDim.x * 256;
  for (; i < 4325376; i += stride) {
    if (i < 4194304) {                  // lower half: d = 0..3, fused
      int d = i >> 20;
      int bt = (i >> 6) & 16383;
      int t = bt & 255;
      int lane = i & 63;
      float vd = 0.f, vo = 0.f;
      if ((t >> 2) == lane)       vd = stage[bt * 16 + d];
      if (((t + 1) >> 2) == lane) vo = stage[bt * 16 + 8 + d];
      int te = t & 3, oe = (t + 1) & 3;
      float4 v;
      v.x = (te == 0 ? vd : 0.f) + (oe == 0 ? vo : 0.f);
      v.y = (te == 1 ? vd : 0.f) + (oe == 1 ? vo : 0.f);
      v.z = (te == 2 ? vd : 0.f) + (oe == 2 ? vo : 0.f);
      v.w = (te == 3 ? vd : 0.f) + (oe == 3 ? vo : 0.f);
      chol[i] = v;
    } else {                            // upper half: scatter d = 4..7
      int j = i - 4194304;              // [0, 131072)
      int bt = j >> 3, q = j & 7;
      int bb = bt >> 8, tt = bt & 255;
      int d = 4 + (q & 3);
      float* ch = (float*)chol;
      if (q < 4) {
        ch[(((size_t)d * 64 + bb) * 256 + tt) * 256 + tt] = stage[bt * 16 + d];
      } else if (tt < 255) {
        ch[(((size_t)d * 64 + bb) * 256 + tt) * 256 + tt + 1] = stage[bt * 16 + 8 + d];
      }
    }
  }
}

extern "C" void kernel_launch(void* const* d_in, const int* in_sizes, int n_in,
                              void* d_out, int out_size, void* d_ws, size_t ws_size,
                              hipStream_t stream) {
  const float* y    = (const float*)d_in[0];
  const float* W_ih = (const float*)d_in[1];
  const float* W_hh = (const float*)d_in[2];
  const float* b_ih = (const float*)d_in[3];
  const float* b_hh = (const float*)d_in[4];
  const float* W_mz = (const float*)d_in[5];
  const float* b_mz = (const float*)d_in[6];
  const float* W_mx = (const float*)d_in[7];
  const float* b_mx = (const float*)d_in[8];
  const float* W_pz = (const float*)d_in[9];
  const float* b_pz = (const float*)d_in[10];
  const float* W_cx = (const float*)d_in[11];
  const float* b_cx = (const float*)d_in[12];

  float* out    = (float*)d_out;
  float* mean_z = out;                    // [64,256,8]
  float* chol   = out + 131072;           // [8,64,256,256]
  float* mean_x = out + 33685504;         // [16384,8]
  float* cov_x  = out + 33816576;         // [16384,8,8]

  float* ws      = (float*)d_ws;
  float* WT_ih   = ws;                    // 98304
  float* WheadT  = ws + 98304;            // 24576
  unsigned* Wreg = (unsigned*)(ws + 122880); // 98304
  float* anchor  = ws + 221184;           // 128
  float* stage   = ws + 221312;           // 262144
  int*   done    = (int*)(ws + 483456);   // 512 flags

  // large scratch inside the chol LOWER half (rewritten by chol_fin at end);
  // upper half [16777216,33554432) is zeroed during the heads launch.
  float* xp  = chol;                      // 12582912 floats
  float* enc = chol + 12582912;           // 4194304 floats (ends at 16777216)

  prep_kernel<<<864, 256, 0, stream>>>(W_ih, W_hh, W_mz, W_mx, W_pz, W_cx,
                                       WT_ih, WheadT, Wreg, done);
  fused_kernel<<<320, 512, 0, stream>>>(y, WT_ih, b_ih, xp, Wreg, b_hh,
                                        enc, done);
  anchor_kernel<<<128, 256, 0, stream>>>(enc, W_mx, b_mx, anchor);
  heads_kernel<<<704, 384, 0, stream>>>(enc, WheadT, b_mz, b_mx, b_pz, b_cx,
                                        anchor, mean_z, mean_x, cov_x, stage,
                                        (float4*)chol);
  chol_fin<<<4096, 256, 0, stream>>>(stage, (float4*)chol);
}

// Round 15
// 599.681 us; speedup vs baseline: 1.2914x; 1.2914x over previous
//
#include <hip/hip_runtime.h>
#include <cstdint>
#include <cstddef>

#define B_   64
#define T_   256
#define DIN_ 128
#define H_   256
#define G3_  768   // 3*H

// ---------- helpers ----------
__device__ __forceinline__ unsigned short f2h(float f) {
  _Float16 h = (_Float16)f;              // v_cvt_f16_f32 (RNE)
  return __builtin_bit_cast(unsigned short, h);
}

// acc += dot(v2f16(a), v2f16(b)) in fp32
__device__ __forceinline__ void dot2f(float& acc, unsigned a, unsigned b) {
  asm("v_dot2_f32_f16 %0, %1, %2, %0" : "+v"(acc) : "v"(a), "v"(b));
}

// ---------- prep ----------
// Wreg layout for 512-thread gru: thread t: ks = t>>7, og = t&127.
// w[j] (j = a*32+qp): Wreg[(j4*512+t)*4+(j&3)] = f16pair(W_hh[a*128+og][64ks+2qp],..+1)
// WheadT layout: [c][k]
__global__ __launch_bounds__(256) void prep_kernel(
    const float* __restrict__ W_ih, const float* __restrict__ W_hh,
    const float* __restrict__ W_mz, const float* __restrict__ W_mx,
    const float* __restrict__ W_pz, const float* __restrict__ W_cx,
    float* __restrict__ WT_ih, float* __restrict__ WheadT,
    unsigned* __restrict__ Wreg) {
  int i = blockIdx.x * 256 + threadIdx.x;
  if (i < 98304) {                       // WT_ih[k*768+g] = W_ih[g*128+k]
    int k = i / 768, g = i % 768;
    WT_ih[i] = W_ih[g * 128 + k];
  } else if (i < 98304 + 24576) {        // WheadT[c*256+k]
    int j = i - 98304;
    int c = j >> 8, k = j & 255;
    float v;
    if (c < 8)       v = W_mz[c * 256 + k];
    else if (c < 16) v = W_mx[(c - 8) * 256 + k];
    else if (c < 32) v = W_pz[(c - 16) * 256 + k];
    else             v = W_cx[(c - 32) * 256 + k];
    WheadT[j] = v;
  } else {                               // W_hh fp16-pair repack
    int m = i - 122880;                  // 0..98303
    int c = m & 3, n = m >> 2;
    int t = n & 511, j4 = n >> 9;        // j4 in [0,48)
    int j = 4 * j4 + c;                  // [0,192)
    int a = j >> 5, qp = j & 31;
    int o = a * 128 + (t & 127);
    int k0 = ((t >> 7) << 6) + 2 * qp;
    unsigned short lo = f2h(W_hh[o * 256 + k0]);
    unsigned short hi = f2h(W_hh[o * 256 + k0 + 1]);
    Wreg[m] = ((unsigned)hi << 16) | (unsigned)lo;
  }
}

// ---------- x_proj = y @ W_ih^T + b_ih : [16384,128]x[128,768] fp32 ----------
__global__ __launch_bounds__(256) void xproj_kernel(
    const float* __restrict__ y, const float* __restrict__ WT_ih,
    const float* __restrict__ b_ih, float* __restrict__ xp) {
  __shared__ float ylds[64][132];
  int tid = threadIdx.x;
  int row0 = blockIdx.x * 64;
  const float4* y4 = (const float4*)(y + (size_t)row0 * DIN_);
#pragma unroll
  for (int i = 0; i < 8; ++i) {
    int idx = i * 256 + tid;             // 2048 float4 = 64x128
    float4 v = y4[idx];
    int r = idx >> 5, c4 = (idx & 31) * 4;
    ylds[r][c4 + 0] = v.x; ylds[r][c4 + 1] = v.y;
    ylds[r][c4 + 2] = v.z; ylds[r][c4 + 3] = v.w;
  }
  __syncthreads();
  int tx = tid & 15, ty = tid >> 4;      // thread: 4 rows x 8 cols
  for (int c = 0; c < 6; ++c) {
    int col0 = c * 128 + tx * 8;
    float acc[4][8];
#pragma unroll
    for (int a = 0; a < 4; ++a)
#pragma unroll
      for (int b = 0; b < 8; ++b) acc[a][b] = 0.f;
#pragma unroll 4
    for (int k = 0; k < 128; ++k) {
      float4 w0 = *(const float4*)&WT_ih[k * 768 + col0];
      float4 w1 = *(const float4*)&WT_ih[k * 768 + col0 + 4];
      float a0 = ylds[ty * 4 + 0][k], a1 = ylds[ty * 4 + 1][k];
      float a2 = ylds[ty * 4 + 2][k], a3 = ylds[ty * 4 + 3][k];
      acc[0][0] += a0 * w0.x; acc[0][1] += a0 * w0.y; acc[0][2] += a0 * w0.z; acc[0][3] += a0 * w0.w;
      acc[0][4] += a0 * w1.x; acc[0][5] += a0 * w1.y; acc[0][6] += a0 * w1.z; acc[0][7] += a0 * w1.w;
      acc[1][0] += a1 * w0.x; acc[1][1] += a1 * w0.y; acc[1][2] += a1 * w0.z; acc[1][3] += a1 * w0.w;
      acc[1][4] += a1 * w1.x; acc[1][5] += a1 * w1.y; acc[1][6] += a1 * w1.z; acc[1][7] += a1 * w1.w;
      acc[2][0] += a2 * w0.x; acc[2][1] += a2 * w0.y; acc[2][2] += a2 * w0.z; acc[2][3] += a2 * w0.w;
      acc[2][4] += a2 * w1.x; acc[2][5] += a2 * w1.y; acc[2][6] += a2 * w1.z; acc[2][7] += a2 * w1.w;
      acc[3][0] += a3 * w0.x; acc[3][1] += a3 * w0.y; acc[3][2] += a3 * w0.z; acc[3][3] += a3 * w0.w;
      acc[3][4] += a3 * w1.x; acc[3][5] += a3 * w1.y; acc[3][6] += a3 * w1.z; acc[3][7] += a3 * w1.w;
    }
    float4 b0 = *(const float4*)&b_ih[col0];
    float4 b1 = *(const float4*)&b_ih[col0 + 4];
#pragma unroll
    for (int a = 0; a < 4; ++a) {
      int row = row0 + ty * 4 + a;
      float4 o0, o1;
      o0.x = acc[a][0] + b0.x; o0.y = acc[a][1] + b0.y; o0.z = acc[a][2] + b0.z; o0.w = acc[a][3] + b0.w;
      o1.x = acc[a][4] + b1.x; o1.y = acc[a][5] + b1.y; o1.z = acc[a][6] + b1.z; o1.w = acc[a][7] + b1.w;
      *(float4*)&xp[(size_t)row * G3_ + col0] = o0;
      *(float4*)&xp[(size_t)row * G3_ + col0 + 4] = o1;
    }
  }
}

// ---------- GRU recurrence: 64 blocks x 512 threads (R11 verbatim) ----------
__global__ __launch_bounds__(512) __attribute__((amdgpu_waves_per_eu(2, 2)))
void gru_kernel(
    const float* __restrict__ xp, const unsigned* Wreg,
    const float* __restrict__ b_hh, float* enc) {
  int tid = threadIdx.x;
  int ks = tid >> 7;                     // wave-uniform k-slice [64ks,64ks+64)
  int og = tid & 127;                    // outputs a*128+og
  int b = blockIdx.x;
  __shared__ alignas(16) unsigned short hsb[256];   // h state, fp16
  __shared__ alignas(16) float part[3104];          // 4 slices x 776 (pad 8)
  unsigned w[192];
  const uint4* W4 = (const uint4*)Wreg;
#pragma unroll
  for (int j4 = 0; j4 < 48; ++j4) {
    uint4 q = W4[j4 * 512 + tid];        // coalesced dwordx4, once
    w[4 * j4 + 0] = q.x; w[4 * j4 + 1] = q.y;
    w[4 * j4 + 2] = q.z; w[4 * j4 + 3] = q.w;
  }
  const float* xpb = xp + (size_t)b * (T_ * G3_);
  float* encb = enc + (size_t)b * (T_ * H_);
  float bhr = 0.f, bhz = 0.f, bhn = 0.f, hold = 0.f;
  float xr0 = 0.f, xz0 = 0.f, xn0 = 0.f, xr1 = 0.f, xz1 = 0.f, xn1 = 0.f;
  if (tid < 256) {
    bhr = b_hh[tid]; bhz = b_hh[256 + tid]; bhn = b_hh[512 + tid];
    xr0 = xpb[tid];        xz0 = xpb[256 + tid];        xn0 = xpb[512 + tid];
    xr1 = xpb[768 + tid];  xz1 = xpb[1024 + tid];       xn1 = xpb[1280 + tid];
    hsb[tid] = 0;                        // h0 = 0
  }
  __syncthreads();
  for (int t = 0; t < T_; ++t) {
    asm volatile("" ::: "memory");       // forbid w[] reload from Wreg
    float xr2 = 0.f, xz2 = 0.f, xn2 = 0.f;
    if (tid < 256) {                     // prefetch t+2 (overrun stays in alloc)
      int base = (t + 2) * G3_ + tid;
      xr2 = xpb[base]; xz2 = xpb[base + 256]; xn2 = xpb[base + 512];
    }
    float p0 = 0.f, p1 = 0.f, p2 = 0.f, p3 = 0.f, p4 = 0.f, p5 = 0.f;
    const uint4* hs = ((const uint4*)hsb) + (ks << 3);   // 8 uint4 = 64 fp16
#pragma unroll
    for (int r = 0; r < 8; ++r) {
      uint4 hq = hs[r];                  // uniform addr -> LDS broadcast
      dot2f(p0, hq.x, w[(r << 2) + 0]);
      dot2f(p0, hq.y, w[(r << 2) + 1]);
      dot2f(p0, hq.z, w[(r << 2) + 2]);
      dot2f(p0, hq.w, w[(r << 2) + 3]);
      dot2f(p1, hq.x, w[32 + (r << 2) + 0]);
      dot2f(p1, hq.y, w[32 + (r << 2) + 1]);
      dot2f(p1, hq.z, w[32 + (r << 2) + 2]);
      dot2f(p1, hq.w, w[32 + (r << 2) + 3]);
      dot2f(p2, hq.x, w[64 + (r << 2) + 0]);
      dot2f(p2, hq.y, w[64 + (r << 2) + 1]);
      dot2f(p2, hq.z, w[64 + (r << 2) + 2]);
      dot2f(p2, hq.w, w[64 + (r << 2) + 3]);
      dot2f(p3, hq.x, w[96 + (r << 2) + 0]);
      dot2f(p3, hq.y, w[96 + (r << 2) + 1]);
      dot2f(p3, hq.z, w[96 + (r << 2) + 2]);
      dot2f(p3, hq.w, w[96 + (r << 2) + 3]);
      dot2f(p4, hq.x, w[128 + (r << 2) + 0]);
      dot2f(p4, hq.y, w[128 + (r << 2) + 1]);
      dot2f(p4, hq.z, w[128 + (r << 2) + 2]);
      dot2f(p4, hq.w, w[128 + (r << 2) + 3]);
      dot2f(p5, hq.x, w[160 + (r << 2) + 0]);
      dot2f(p5, hq.y, w[160 + (r << 2) + 1]);
      dot2f(p5, hq.z, w[160 + (r << 2) + 2]);
      dot2f(p5, hq.w, w[160 + (r << 2) + 3]);
    }
    int pb = ks * 776 + og;
    part[pb]       = p0;  part[pb + 128] = p1;
    part[pb + 256] = p2;  part[pb + 384] = p3;
    part[pb + 512] = p4;  part[pb + 640] = p5;
    __syncthreads();                     // partials visible; h reads done
    if (tid < 256) {
      int u = tid;
      float prer = bhr + ((part[u] + part[776 + u]) +
                          (part[1552 + u] + part[2328 + u]));
      float prez = bhz + ((part[256 + u] + part[1032 + u]) +
                          (part[1808 + u] + part[2584 + u]));
      float pren = bhn + ((part[512 + u] + part[1288 + u]) +
                          (part[2064 + u] + part[2840 + u]));
      float r_ = 1.f / (1.f + __expf(-(xr0 + prer)));
      float z_ = 1.f / (1.f + __expf(-(xz0 + prez)));
      float a = xn0 + r_ * pren;
      a = fminf(15.f, fmaxf(-15.f, a));
      float e = __expf(2.f * a);
      float n = (e - 1.f) / (e + 1.f);   // tanh
      float hnew = (1.f - z_) * n + z_ * hold;
      hold = hnew;                       // exact fp32 state in-register
      encb[t * H_ + u] = hnew;
      hsb[u] = f2h(hnew);
      xr0 = xr1; xz0 = xz1; xn0 = xn1;
      xr1 = xr2; xz1 = xz2; xn1 = xn2;
    }
    __syncthreads();                     // new h visible; part consumed
  }
}

// ---------- heads (0-511) + upper-half chol zero (512-703) + anchor (704-831) ---
// heads writes mean_x WITHOUT the anchor subtraction (applied in chol_fin).
__global__ __launch_bounds__(384) void heads_kernel(
    const float* __restrict__ enc, const float* __restrict__ WheadT,
    const float* __restrict__ b_mz, const float* __restrict__ b_mx,
    const float* __restrict__ b_pz, const float* __restrict__ b_cx,
    float* __restrict__ out_meanz, float* __restrict__ out_meanx,
    float* __restrict__ out_covx, float* __restrict__ stage,
    float4* __restrict__ chol4, float* __restrict__ anchor,
    const float* __restrict__ W_mx) {
  int tid = threadIdx.x;
  if (blockIdx.x >= 704) {               // ---- anchor: block = (b,d)
    __shared__ float red[4];
    int bid = blockIdx.x - 704;
    int b = bid >> 1, d = bid & 1;
    if (tid < 256) {
      float v = enc[(size_t)b * (T_ * H_) + tid] * W_mx[d * 256 + tid];
#pragma unroll
      for (int off = 32; off >= 1; off >>= 1) v += __shfl_down(v, off, 64);
      if ((tid & 63) == 0) red[tid >> 6] = v;
    }
    __syncthreads();
    if (tid == 0)
      anchor[b * 2 + d] = b_mx[d] + ((red[0] + red[1]) + (red[2] + red[3]));
    return;
  }
  if (blockIdx.x >= 512) {               // ---- zero chol floats [16777216, 33554432)
    float4* cz = chol4 + 4194304;
    int idx = (blockIdx.x - 512) * 384 + tid;
    float4 z = {0.f, 0.f, 0.f, 0.f};
    for (; idx < 4194304; idx += 192 * 384) cz[idx] = z;
    return;
  }
  __shared__ float el[32 * 256];         // 32 KB
  int row0 = blockIdx.x * 32;
  const float4* e4 = (const float4*)(enc + (size_t)row0 * 256);
  float4* el4 = (float4*)el;
#pragma unroll
  for (int i = 0; i < 6; ++i) {
    int idx = i * 384 + tid;             // 2048 float4 = 32x64
    if (idx < 2048) el4[idx] = e4[idx];
  }
  __syncthreads();
  int rg = tid / 96, c = tid - rg * 96;  // rg in [0,4), c in [0,96)
  const float4* Wc = (const float4*)(WheadT + c * 256);
  float acc[8];
#pragma unroll
  for (int r = 0; r < 8; ++r) acc[r] = 0.f;
  for (int k4 = 0; k4 < 64; ++k4) {
    float4 w4 = Wc[k4];
#pragma unroll
    for (int r = 0; r < 8; ++r) {
      float4 ev = el4[(rg * 8 + r) * 64 + k4];
      acc[r] += w4.x * ev.x; acc[r] += w4.y * ev.y;
      acc[r] += w4.z * ev.z; acc[r] += w4.w * ev.w;
    }
  }
#pragma unroll
  for (int r = 0; r < 8; ++r) {
    int row = row0 + rg * 8 + r;
    float a_ = acc[r];
    if (c < 8) {
      out_meanz[(size_t)row * 8 + c] = a_ + b_mz[c];
    } else if (c < 16) {
      int d = c - 8;
      out_meanx[(size_t)row * 8 + d] = a_ + b_mx[d];   // anchor applied later
    } else if (c < 32) {
      int d = c - 16;
      float v = a_ + b_pz[d];
      if (d < 8)                          // diag: softplus (stable)
        v = (v > 0.f) ? (v + log1pf(__expf(-v))) : log1pf(__expf(v));
      stage[(size_t)row * 16 + d] = v;
    } else {
      int d = c - 32;
      out_covx[(size_t)row * 64 + d] = a_ + b_cx[d];
    }
  }
}

// ---------- final: fused zero+scatter lower chol, upper scatter, mean_x fix ----
__global__ __launch_bounds__(256) void chol_fin(
    const float* __restrict__ stage, float4* __restrict__ chol,
    const float* __restrict__ anchor, float* __restrict__ mean_x) {
  int i = blockIdx.x * 256 + threadIdx.x;
  int stride = gridDim.x * 256;
  for (; i < 4358144; i += stride) {
    if (i < 4194304) {                  // lower half: d = 0..3, fused zero+scatter
      int d = i >> 20;
      int bt = (i >> 6) & 16383;
      int t = bt & 255;
      int lane = i & 63;
      float vd = 0.f, vo = 0.f;
      if ((t >> 2) == lane)       vd = stage[bt * 16 + d];
      if (((t + 1) >> 2) == lane) vo = stage[bt * 16 + 8 + d];
      int te = t & 3, oe = (t + 1) & 3;
      float4 v;
      v.x = (te == 0 ? vd : 0.f) + (oe == 0 ? vo : 0.f);
      v.y = (te == 1 ? vd : 0.f) + (oe == 1 ? vo : 0.f);
      v.z = (te == 2 ? vd : 0.f) + (oe == 2 ? vo : 0.f);
      v.w = (te == 3 ? vd : 0.f) + (oe == 3 ? vo : 0.f);
      chol[i] = v;
    } else if (i < 4325376) {           // upper half: scatter d = 4..7
      int j = i - 4194304;              // [0, 131072)
      int bt = j >> 3, q = j & 7;
      int bb = bt >> 8, tt = bt & 255;
      int d = 4 + (q & 3);
      float* ch = (float*)chol;
      if (q < 4) {
        ch[(((size_t)d * 64 + bb) * 256 + tt) * 256 + tt] = stage[bt * 16 + d];
      } else if (tt < 255) {
        ch[(((size_t)d * 64 + bb) * 256 + tt) * 256 + tt + 1] = stage[bt * 16 + 8 + d];
      }
    } else {                            // deferred anchor subtraction on mean_x
      int j2 = i - 4325376;             // [0, 32768)
      int row = j2 >> 1, d = j2 & 1;
      mean_x[(size_t)row * 8 + d] -= anchor[(row >> 8) * 2 + d];
    }
  }
}

extern "C" void kernel_launch(void* const* d_in, const int* in_sizes, int n_in,
                              void* d_out, int out_size, void* d_ws, size_t ws_size,
                              hipStream_t stream) {
  const float* y    = (const float*)d_in[0];
  const float* W_ih = (const float*)d_in[1];
  const float* W_hh = (const float*)d_in[2];
  const float* b_ih = (const float*)d_in[3];
  const float* b_hh = (const float*)d_in[4];
  const float* W_mz = (const float*)d_in[5];
  const float* b_mz = (const float*)d_in[6];
  const float* W_mx = (const float*)d_in[7];
  const float* b_mx = (const float*)d_in[8];
  const float* W_pz = (const float*)d_in[9];
  const float* b_pz = (const float*)d_in[10];
  const float* W_cx = (const float*)d_in[11];
  const float* b_cx = (const float*)d_in[12];

  float* out    = (float*)d_out;
  float* mean_z = out;                    // [64,256,8]
  float* chol   = out + 131072;           // [8,64,256,256]
  float* mean_x = out + 33685504;         // [16384,8]
  float* cov_x  = out + 33816576;         // [16384,8,8]

  float* ws      = (float*)d_ws;
  float* WT_ih   = ws;                    // 98304
  float* WheadT  = ws + 98304;            // 24576
  unsigned* Wreg = (unsigned*)(ws + 122880); // 98304
  float* anchor  = ws + 221184;           // 128
  float* stage   = ws + 221312;           // 262144

  // large scratch inside the chol LOWER half (rewritten by chol_fin at end);
  // upper half [16777216,33554432) is zeroed during the heads launch.
  float* xp  = chol;                      // 12582912 floats
  float* enc = chol + 12582912;           // 4194304 floats (ends at 16777216)

  prep_kernel<<<864, 256, 0, stream>>>(W_ih, W_hh, W_mz, W_mx, W_pz, W_cx,
                                       WT_ih, WheadT, Wreg);
  xproj_kernel<<<256, 256, 0, stream>>>(y, WT_ih, b_ih, xp);
  gru_kernel<<<64, 512, 0, stream>>>(xp, Wreg, b_hh, enc);
  heads_kernel<<<832, 384, 0, stream>>>(enc, WheadT, b_mz, b_mx, b_pz, b_cx,
                                        mean_z, mean_x, cov_x, stage,
                                        (float4*)chol, anchor, W_mx);
  chol_fin<<<4096, 256, 0, stream>>>(stage, (float4*)chol, anchor, mean_x);
}